// Round 2
// 396.735 us; speedup vs baseline: 1.0158x; 1.0158x over previous
//
#include <hip/hip_runtime.h>
#include <math.h>

// Problem constants: [b, seq, heads, head_dim] = [4, 8192, 16, 64], f32.
// NOTE: resubmission of round-1 kernel — previous bench died with an
// infrastructure error (container failed), never measured.
#define BB 4
#define SS 8192
#define HH 16
#define DDIM 64

// ws layout (floats):
//   [0, 6144)        sums[3][4][8][64]   (group, batch, qh(padded to 8), d)
//   X0 @ 6144        [4][8192][6][64]    group 0 pre-norm x
//   X1 after X0      [4][4096][5][64]    group 1
//   X2 after X1      [4][2048][5][64]    group 2
static const long X0_OFF = 6144;
static const long X0_SZ = 4L * 8192 * 6 * 64;
static const long X1_OFF = X0_OFF + X0_SZ;
static const long X1_SZ = 4L * 4096 * 5 * 64;
static const long X2_OFF = X1_OFF + X1_SZ;
static const long X2_SZ = 4L * 2048 * 5 * 64;
static const long WS_FLOATS = X2_OFF + X2_SZ;   // ~20.45M floats = 81.8 MB

__global__ __launch_bounds__(256) void k_zero_sums(float* ws) {
    int idx = blockIdx.x * 256 + threadIdx.x;
    if (idx < 6144) ws[idx] = 0.0f;
}

__device__ __forceinline__ float4 shfl_xor4(float4 v, int m) {
    return make_float4(__shfl_xor(v.x, m, 64), __shfl_xor(v.y, m, 64),
                       __shfl_xor(v.z, m, 64), __shfl_xor(v.w, m, 64));
}

// Pass 1: per-position head-group attention.
// Lane layout: lane = (posInWave<<4) | d4  -> 16 lanes own one position's 64-d.
// ILP-restructured: all loads issued up front; butterfly reduces are
// stage-outer so all 36 scores advance in parallel (spend VGPRs for ILP).
__global__ __launch_bounds__(256) void k_attn(const float* __restrict__ Q,
                                              const float* __restrict__ Kp,
                                              const float* __restrict__ Vp,
                                              float* __restrict__ ws) {
    __shared__ __align__(16) float psum[4][6][64];  // wave, qh, d

    int bid = blockIdx.x;
    int gi, b, tile, g, r, off, hmin, J;
    long xoff;
    if (bid < 2048)      { gi = 0; b = bid >> 9; tile = bid & 511; g = 6; r = 1; off = 0; hmin = 0;  J = 8192; xoff = X0_OFF; }
    else if (bid < 3072) { gi = 1; bid -= 2048; b = bid >> 8; tile = bid & 255; g = 5; r = 2; off = 1; hmin = 5;  J = 4096; xoff = X1_OFF; }
    else                 { gi = 2; bid -= 3072; b = bid >> 7; tile = bid & 127; g = 5; r = 4; off = 2; hmin = 10; J = 2048; xoff = X2_OFF; }

    const int t = threadIdx.x;
    const int lane = t & 63;
    const int wave = t >> 6;
    const int d4 = t & 15;          // which float4 of the 64-d row
    const int pIdx = t >> 4;        // position within block (0..15)
    const int j = tile * 16 + pIdx; // strided-view position index
    const int pos = off + j * r;    // real sequence position

    const long rowbase = (((long)b * SS + pos) * HH + hmin) * DDIM;
    const float4* q4p = (const float4*)(Q + rowbase);
    const float4* k4p = (const float4*)(Kp + rowbase);
    const float4* v4p = (const float4*)(Vp + rowbase);

    // Phase 0: issue ALL loads (q,k,v) before any compute — max bytes in flight.
    float4 q4[6], k4[6], v4[6];
#pragma unroll
    for (int hh = 0; hh < 6; ++hh) {
        if (hh < g) {
            q4[hh] = q4p[hh * 16 + d4];
            k4[hh] = k4p[hh * 16 + d4];
            v4[hh] = v4p[hh * 16 + d4];
        } else {
            q4[hh] = make_float4(0.f, 0.f, 0.f, 0.f);
            k4[hh] = q4[hh];
            v4[hh] = q4[hh];
        }
    }

    // Phase 1: 36 per-lane partial dot products (q,k die after this).
    float pp[6][6];
#pragma unroll
    for (int qh = 0; qh < 6; ++qh)
#pragma unroll
        for (int kh = 0; kh < 6; ++kh)
            pp[qh][kh] = q4[qh].x * k4[kh].x + q4[qh].y * k4[kh].y +
                         q4[qh].z * k4[kh].z + q4[qh].w * k4[kh].w;

    // Phase 2: butterfly reduce over the 16 d4-lanes — stage-outer so all
    // 36 values advance in parallel (36 independent shfls per stage).
#pragma unroll
    for (int m = 1; m <= 8; m <<= 1) {
#pragma unroll
        for (int qh = 0; qh < 6; ++qh)
#pragma unroll
            for (int kh = 0; kh < 6; ++kh)
                pp[qh][kh] += __shfl_xor(pp[qh][kh], m, 64);
    }

    // Phase 3: softmax over kh per qh (duplicated across 16 d4 lanes; cheap).
#pragma unroll
    for (int qh = 0; qh < 6; ++qh) {
        if (qh >= g) continue;
        float mx = pp[qh][0];
#pragma unroll
        for (int kh = 1; kh < 6; ++kh)
            if (kh < g) mx = fmaxf(mx, pp[qh][kh]);
        float den = 0.0f;
#pragma unroll
        for (int kh = 0; kh < 6; ++kh) {
            if (kh < g) { pp[qh][kh] = __expf((pp[qh][kh] - mx) * 0.125f); den += pp[qh][kh]; }
        }
        float rden = __frcp_rn(den);
#pragma unroll
        for (int kh = 0; kh < 6; ++kh) pp[qh][kh] *= rden;
    }

    // Phase 4: x = attn @ V ; dense 256B stores.
    float4* xrow = (float4*)(ws + xoff + (((long)b * J + j) * g) * DDIM);
    float4 o[6];
#pragma unroll
    for (int qh = 0; qh < 6; ++qh) {
        float4 acc = make_float4(0.f, 0.f, 0.f, 0.f);
        if (qh < g) {
#pragma unroll
            for (int kh = 0; kh < 6; ++kh) {
                if (kh < g) {
                    acc.x += pp[qh][kh] * v4[kh].x; acc.y += pp[qh][kh] * v4[kh].y;
                    acc.z += pp[qh][kh] * v4[kh].z; acc.w += pp[qh][kh] * v4[kh].w;
                }
            }
            xrow[qh * 16 + d4] = acc;
        }
        o[qh] = acc;
    }

    // Phase 5: sum over the wave's 4 positions (lane bits 4,5) — stage-outer,
    // all 6 qh reduce in parallel.
#pragma unroll
    for (int m = 16; m <= 32; m <<= 1) {
#pragma unroll
        for (int qh = 0; qh < 6; ++qh) {
            float4 tmp = shfl_xor4(o[qh], m);
            o[qh].x += tmp.x; o[qh].y += tmp.y; o[qh].z += tmp.z; o[qh].w += tmp.w;
        }
    }
    if (lane < 16) {
#pragma unroll
        for (int qh = 0; qh < 6; ++qh)
            ((float4*)&psum[wave][qh][0])[d4] = o[qh];
    }
    __syncthreads();

    // combine 4 waves; one atomic per (qh,d) per block
    for (int idx = t; idx < g * 64; idx += 256) {
        int qh = idx >> 6, dd = idx & 63;
        float v = psum[0][qh][dd] + psum[1][qh][dd] + psum[2][qh][dd] + psum[3][qh][dd];
        unsafeAtomicAdd(ws + ((long)(gi * 4 + b) * 8 + qh) * 64 + dd, v);
    }
}

// Pass 2: gather + normalize. Block = 8 consecutive (b,pos); 32KB contiguous
// writes. ILP-restructured: all 14 conditional X loads hoisted before the
// store loop; reciprocal of sums folded in here (k_recip launch removed).
__global__ __launch_bounds__(256) void k_out(const float* __restrict__ ws,
                                             float* __restrict__ out) {
    const int t = threadIdx.x;
    const int bid = blockIdx.x;
    const int dd4 = t & 15;
    const int h = t >> 4;
    const int b = bid >> 10;           // 1024 position-blocks per batch
    const int pos0 = (bid & 1023) * 8;

    const bool has0 = (h < 6);
    const bool has1 = (h >= 5 && h <= 9);
    const bool has2 = (h >= 10 && h <= 14);

    // raw sums (recip computed inline below); depend only on (group,b,head)
    float4 rs0 = make_float4(1.f, 1.f, 1.f, 1.f), rs1 = rs0, rs2 = rs0;
    if (has0) rs0 = ((const float4*)(ws + ((long)(0 * 4 + b) * 8 + h) * 64))[dd4];
    if (has1) rs1 = ((const float4*)(ws + ((long)(1 * 4 + b) * 8 + (h - 5)) * 64))[dd4];
    if (has2) rs2 = ((const float4*)(ws + ((long)(2 * 4 + b) * 8 + (h - 10)) * 64))[dd4];

    // Hoist ALL X loads for this thread's 8 positions (issued concurrently).
    float4 x0[8], x1[4], x2[2];
    if (has0) {
#pragma unroll
        for (int pp = 0; pp < 8; ++pp)
            x0[pp] = ((const float4*)(ws + X0_OFF + (((long)b * 8192 + pos0 + pp) * 6 + h) * 64))[dd4];
    }
    if (has1) {
#pragma unroll
        for (int q = 0; q < 4; ++q) {   // odd positions: pos = pos0+2q+1, jj = pos>>1
            int jj = (pos0 >> 1) + q;
            x1[q] = ((const float4*)(ws + X1_OFF + (((long)b * 4096 + jj) * 5 + (h - 5)) * 64))[dd4];
        }
    }
    if (has2) {
#pragma unroll
        for (int q = 0; q < 2; ++q) {   // pos%4==2: pos = pos0+4q+2, jj = pos>>2
            int jj = (pos0 >> 2) + q;
            x2[q] = ((const float4*)(ws + X2_OFF + (((long)b * 2048 + jj) * 5 + (h - 10)) * 64))[dd4];
        }
    }

    // reciprocal of the sums (12 rcp per thread — cheap, replaces k_recip)
    if (has0) { rs0.x = __frcp_rn(rs0.x); rs0.y = __frcp_rn(rs0.y); rs0.z = __frcp_rn(rs0.z); rs0.w = __frcp_rn(rs0.w); }
    if (has1) { rs1.x = __frcp_rn(rs1.x); rs1.y = __frcp_rn(rs1.y); rs1.z = __frcp_rn(rs1.z); rs1.w = __frcp_rn(rs1.w); }
    if (has2) { rs2.x = __frcp_rn(rs2.x); rs2.y = __frcp_rn(rs2.y); rs2.z = __frcp_rn(rs2.z); rs2.w = __frcp_rn(rs2.w); }

    const float third = 1.0f / 3.0f;
#pragma unroll
    for (int pp = 0; pp < 8; ++pp) {
        float4 r = make_float4(0.f, 0.f, 0.f, 0.f);

        if (has0) {  // group 0: all positions, heads 0..5
            r.x += x0[pp].x * rs0.x; r.y += x0[pp].y * rs0.y;
            r.z += x0[pp].z * rs0.z; r.w += x0[pp].w * rs0.w;
        }
        if (has1 && (pp & 1) == 1) {  // group 1: odd positions
            int q = pp >> 1;
            r.x += x1[q].x * rs1.x; r.y += x1[q].y * rs1.y;
            r.z += x1[q].z * rs1.z; r.w += x1[q].w * rs1.w;
        }
        if (has2 && (pp & 3) == 2) {  // group 2: pos%4==2
            int q = pp >> 2;
            r.x += x2[q].x * rs2.x; r.y += x2[q].y * rs2.y;
            r.z += x2[q].z * rs2.z; r.w += x2[q].w * rs2.w;
        }

        r.x *= third; r.y *= third; r.z *= third; r.w *= third;
        ((float4*)out)[((long)(b * 8192 + pos0 + pp)) * 256 + t] = r;
    }
}

extern "C" void kernel_launch(void* const* d_in, const int* in_sizes, int n_in,
                              void* d_out, int out_size, void* d_ws, size_t ws_size,
                              hipStream_t stream) {
    const float* Q = (const float*)d_in[0];
    const float* K = (const float*)d_in[1];
    const float* V = (const float*)d_in[2];
    float* ws = (float*)d_ws;
    float* out = (float*)d_out;

    if (ws_size < (size_t)WS_FLOATS * sizeof(float)) return;  // need ~82 MB scratch

    k_zero_sums<<<24, 256, 0, stream>>>(ws);
    k_attn<<<3584, 256, 0, stream>>>(Q, K, V, ws);
    k_out<<<4096, 256, 0, stream>>>(ws, out);
}